// Round 1
// baseline (555.354 us; speedup 1.0000x reference)
//
#include <hip/hip_runtime.h>
#include <hip/hip_bf16.h>
#include <stdint.h>

#define B_ 4
#define T_ 2048
#define C_ 1024
#define H_ 16
#define DH_ 64
#define M_ (B_*T_)      // 8192
#define NQKV_ (3*C_)    // 3072
#define K_ C_           // 1024

typedef __attribute__((ext_vector_type(8))) short short8;
typedef __attribute__((ext_vector_type(4))) float f32x4;
typedef __attribute__((ext_vector_type(4))) unsigned short us4;

union BFC { __hip_bfloat16 h; unsigned short u; };
__device__ inline unsigned short f2b(float f){ BFC c; c.h = __float2bfloat16(f); return c.u; }

__device__ inline void gload_lds16(const void* g, void* l){
  __builtin_amdgcn_global_load_lds(
    (const __attribute__((address_space(1))) void*)(uintptr_t)g,
    (__attribute__((address_space(3))) void*)(uintptr_t)l,
    16, 0, 0);
}

// ---------------- fp32 -> bf16 convert ----------------
__global__ void cvt_f32_bf16(const float* __restrict__ src,
                             __hip_bfloat16* __restrict__ dst, int n4)
{
  int i = blockIdx.x * blockDim.x + threadIdx.x;
  int stride = gridDim.x * blockDim.x;
  for (; i < n4; i += stride) {
    float4 v = reinterpret_cast<const float4*>(src)[i];
    us4 o;
    o.x = f2b(v.x); o.y = f2b(v.y); o.z = f2b(v.z); o.w = f2b(v.w);
    reinterpret_cast<us4*>(dst)[i] = o;
  }
}

// ---------------- GEMM: Y[M,N] = A[M,K] * B[N,K]^T + bias ----------------
// tile 128x128, BK=32, 4 waves (2x2), each wave 64x64 (4x4 of 16x16x32 MFMA)
// LDS layout [128][32] bf16 with XOR swizzle: colbyte ^= ((row>>1)&3)<<4
// staging via global_load_lds(16B) with inverse-swizzled global source.
__global__ __launch_bounds__(256) void gemm_bt(
    const __hip_bfloat16* __restrict__ A,
    const __hip_bfloat16* __restrict__ Bw,
    const float* __restrict__ bias,
    int mode,
    __hip_bfloat16* __restrict__ qdst,
    __hip_bfloat16* __restrict__ kdst,
    __hip_bfloat16* __restrict__ vdst,
    float* __restrict__ fdst)
{
  __shared__ char a_lds[8192];
  __shared__ char b_lds[8192];

  const int tid = threadIdx.x;
  const int lane = tid & 63;
  const int w = tid >> 6;
  const int l15 = lane & 15;
  const int lhi = lane >> 4;
  const int wm = w >> 1, wn = w & 1;
  const int row0 = blockIdx.y * 128;
  const int col0 = blockIdx.x * 128;

  // staging address decode (linear LDS byte -> logical (row, k))
  int srow[2], scol[2];
#pragma unroll
  for (int j = 0; j < 2; ++j) {
    int L = w * 2048 + j * 1024 + lane * 16;
    int r = L >> 6;
    int cb = (L & 63) ^ (((r >> 1) & 3) << 4);
    srow[j] = r;
    scol[j] = cb >> 1;
  }

  const f32x4 zf = {0.f, 0.f, 0.f, 0.f};
  f32x4 acc[4][4];
#pragma unroll
  for (int m = 0; m < 4; ++m)
#pragma unroll
    for (int n = 0; n < 4; ++n) acc[m][n] = zf;

  const short* Ag = (const short*)A;
  const short* Bg = (const short*)Bw;

  for (int kt = 0; kt < K_; kt += 32) {
    gload_lds16(Ag + (size_t)(row0 + srow[0]) * K_ + kt + scol[0], a_lds + w * 2048);
    gload_lds16(Ag + (size_t)(row0 + srow[1]) * K_ + kt + scol[1], a_lds + w * 2048 + 1024);
    gload_lds16(Bg + (size_t)(col0 + srow[0]) * K_ + kt + scol[0], b_lds + w * 2048);
    gload_lds16(Bg + (size_t)(col0 + srow[1]) * K_ + kt + scol[1], b_lds + w * 2048 + 1024);
    __syncthreads();

    short8 af[4], bfr[4];
#pragma unroll
    for (int m = 0; m < 4; ++m) {
      int r = wm * 64 + m * 16 + l15;
      af[m] = *(const short8*)(a_lds + r * 64 + ((lhi * 16) ^ (((r >> 1) & 3) << 4)));
    }
#pragma unroll
    for (int n = 0; n < 4; ++n) {
      int r = wn * 64 + n * 16 + l15;
      bfr[n] = *(const short8*)(b_lds + r * 64 + ((lhi * 16) ^ (((r >> 1) & 3) << 4)));
    }
#pragma unroll
    for (int m = 0; m < 4; ++m)
#pragma unroll
      for (int n = 0; n < 4; ++n)
        acc[m][n] = __builtin_amdgcn_mfma_f32_16x16x32_bf16(af[m], bfr[n], acc[m][n], 0, 0, 0);
    __syncthreads();
  }

  if (mode == 0) {
    // scatter into Q/K/V [B,H,T,DH] bf16, add bias
#pragma unroll
    for (int m = 0; m < 4; ++m) {
#pragma unroll
      for (int r = 0; r < 4; ++r) {
        int grow = row0 + wm * 64 + m * 16 + lhi * 4 + r;
        int b = grow >> 11, tt = grow & 2047;
#pragma unroll
        for (int n = 0; n < 4; ++n) {
          int gcol = col0 + wn * 64 + n * 16 + l15;
          float v = acc[m][n][r] + bias[gcol];
          int sel = gcol >> 10;
          int c1 = gcol & 1023;
          int hh = c1 >> 6, dh = c1 & 63;
          __hip_bfloat16* dst = sel == 0 ? qdst : (sel == 1 ? kdst : vdst);
          dst[(((size_t)(b * H_ + hh)) * T_ + tt) * DH_ + dh] = __float2bfloat16(v);
        }
      }
    }
  } else {
    // fp32 out + bias
#pragma unroll
    for (int m = 0; m < 4; ++m) {
#pragma unroll
      for (int r = 0; r < 4; ++r) {
        int grow = row0 + wm * 64 + m * 16 + lhi * 4 + r;
#pragma unroll
        for (int n = 0; n < 4; ++n) {
          int gcol = col0 + wn * 64 + n * 16 + l15;
          fdst[(size_t)grow * C_ + gcol] = acc[m][n][r] + bias[gcol];
        }
      }
    }
  }
}

// ---------------- causal flash attention ----------------
// block = 64 q rows (4 waves x 16 rows), KVBLK = 64, DH = 64
__global__ __launch_bounds__(256) void attn_kernel(
    const __hip_bfloat16* __restrict__ qg,
    const __hip_bfloat16* __restrict__ kg,
    const __hip_bfloat16* __restrict__ vg,
    __hip_bfloat16* __restrict__ og)
{
  __shared__ char k_lds[64 * 128];   // [kv][dh] bf16, swizzle (row&7)<<4
  __shared__ char v_lds[64 * 128];   // [dh][kv] bf16 (V^T), swizzle (dh&7)<<4
  __shared__ char p_lds[4 * 2048];   // per-wave [16][64] bf16, swizzle ((row^(row>>3))&7)<<4

  const int tid = threadIdx.x;
  const int lane = tid & 63;
  const int w = tid >> 6;
  const int l15 = lane & 15;
  const int lhi = lane >> 4;
  const int blk = blockIdx.x;
  const int bh = blk >> 5;
  const int qblk = blk & 31;
  const int q0 = qblk * 64;

  const short* qp = (const short*)(qg + (size_t)bh * T_ * DH_);
  const short* kp = (const short*)(kg + (size_t)bh * T_ * DH_);
  const short* vp = (const short*)(vg + (size_t)bh * T_ * DH_);

  // Q fragments held in registers: rows q0 + w*16 + l15
  short8 qf[2];
  {
    const short* qr = qp + (size_t)(q0 + w * 16 + l15) * DH_;
    qf[0] = *(const short8*)(qr + lhi * 8);
    qf[1] = *(const short8*)(qr + lhi * 8 + 32);
  }

  const f32x4 zf = {0.f, 0.f, 0.f, 0.f};
  f32x4 o[4];
#pragma unroll
  for (int n = 0; n < 4; ++n) o[n] = zf;
  float mrow[4], lrow[4];
#pragma unroll
  for (int r = 0; r < 4; ++r) { mrow[r] = -1e30f; lrow[r] = 0.f; }

  const int ntiles = qblk + 1;
  for (int t = 0; t < ntiles; ++t) {
    const int kv0 = t * 64;
    {
      // stage K tile [64][64] bf16 row-major, swizzled
      const char* src = (const char*)(kp + (size_t)kv0 * DH_);
      int row = tid >> 2;
      int cb0 = (tid & 3) << 5;
#pragma unroll
      for (int c = 0; c < 2; ++c) {
        int cb = cb0 + c * 16;
        short8 val = *(const short8*)(src + row * 128 + cb);
        *(short8*)(k_lds + row * 128 + (cb ^ ((row & 7) << 4))) = val;
      }
      // stage V^T tile [dh][kv], packed u32 (2 kv per write)
      const unsigned short* vsrc = (const unsigned short*)(vp + (size_t)kv0 * DH_);
#pragma unroll
      for (int i = 0; i < 8; ++i) {
        int u = i * 256 + tid;
        int dh = u & 63;
        int kvp = u >> 6;  // 0..31
        unsigned int e0 = vsrc[(2 * kvp) * 64 + dh];
        unsigned int e1 = vsrc[(2 * kvp + 1) * 64 + dh];
        *(unsigned int*)(v_lds + dh * 128 + ((kvp * 4) ^ ((dh & 7) << 4))) =
            e0 | (e1 << 16);
      }
    }
    __syncthreads();

    // S = Q K^T
    f32x4 s[4];
#pragma unroll
    for (int n = 0; n < 4; ++n) s[n] = zf;
#pragma unroll
    for (int kf = 0; kf < 2; ++kf) {
#pragma unroll
      for (int n = 0; n < 4; ++n) {
        int kr = n * 16 + l15;
        short8 bfr = *(const short8*)(k_lds + kr * 128 +
                                      ((lhi * 16 + kf * 64) ^ ((kr & 7) << 4)));
        s[n] = __builtin_amdgcn_mfma_f32_16x16x32_bf16(qf[kf], bfr, s[n], 0, 0, 0);
      }
    }
    const float scale = 0.125f;  // DH^-0.5
#pragma unroll
    for (int n = 0; n < 4; ++n)
#pragma unroll
      for (int r = 0; r < 4; ++r) s[n][r] *= scale;

    if (t == ntiles - 1) {
#pragma unroll
      for (int n = 0; n < 4; ++n)
#pragma unroll
        for (int r = 0; r < 4; ++r) {
          int kvA = kv0 + n * 16 + l15;
          int qA = q0 + w * 16 + lhi * 4 + r;
          if (kvA > qA) s[n][r] = -1e30f;
        }
    }

    // online softmax (row stats across 16-lane groups)
    float pm[4];
#pragma unroll
    for (int r = 0; r < 4; ++r)
      pm[r] = fmaxf(fmaxf(s[0][r], s[1][r]), fmaxf(s[2][r], s[3][r]));
#pragma unroll
    for (int r = 0; r < 4; ++r)
#pragma unroll
      for (int d = 1; d < 16; d <<= 1)
        pm[r] = fmaxf(pm[r], __shfl_xor(pm[r], d, 64));

    float alpha[4];
#pragma unroll
    for (int r = 0; r < 4; ++r) {
      float mn = fmaxf(mrow[r], pm[r]);
      alpha[r] = __expf(mrow[r] - mn);
      mrow[r] = mn;
    }
    float p[4][4];
    float rs[4] = {0.f, 0.f, 0.f, 0.f};
#pragma unroll
    for (int n = 0; n < 4; ++n)
#pragma unroll
      for (int r = 0; r < 4; ++r) {
        float pe = __expf(s[n][r] - mrow[r]);
        p[n][r] = pe;
        rs[r] += pe;
      }
#pragma unroll
    for (int r = 0; r < 4; ++r) {
#pragma unroll
      for (int d = 1; d < 16; d <<= 1) rs[r] += __shfl_xor(rs[r], d, 64);
      lrow[r] = lrow[r] * alpha[r] + rs[r];
    }
#pragma unroll
    for (int n = 0; n < 4; ++n)
#pragma unroll
      for (int r = 0; r < 4; ++r) o[n][r] *= alpha[r];

    // P -> per-wave LDS (bf16, swizzled), then read as MFMA A fragments
    char* pw = p_lds + w * 2048;
#pragma unroll
    for (int n = 0; n < 4; ++n)
#pragma unroll
      for (int r = 0; r < 4; ++r) {
        int row = lhi * 4 + r;
        int swz = ((row ^ (row >> 3)) & 7) << 4;
        *(unsigned short*)(pw + row * 128 + (((n * 16 + l15) * 2) ^ swz)) =
            f2b(p[n][r]);
      }
    short8 pa[2];
#pragma unroll
    for (int kf = 0; kf < 2; ++kf) {
      int row = l15;
      int swz = ((row ^ (row >> 3)) & 7) << 4;
      pa[kf] = *(const short8*)(pw + row * 128 + ((lhi * 16 + kf * 64) ^ swz));
    }
    // O += P V
#pragma unroll
    for (int kf = 0; kf < 2; ++kf) {
#pragma unroll
      for (int n = 0; n < 4; ++n) {
        int dh = n * 16 + l15;
        short8 vfr = *(const short8*)(v_lds + dh * 128 +
                                      ((kf * 64 + lhi * 16) ^ ((dh & 7) << 4)));
        o[n] = __builtin_amdgcn_mfma_f32_16x16x32_bf16(pa[kf], vfr, o[n], 0, 0, 0);
      }
    }
    __syncthreads();
  }

  // epilogue: O/l -> att [B,T,C] bf16 (c = h*64+dh)
  const int b = bh >> 4, h = bh & 15;
#pragma unroll
  for (int r = 0; r < 4; ++r) {
    float inv = 1.f / lrow[r];
    int qrow = q0 + w * 16 + lhi * 4 + r;
    __hip_bfloat16* orow = og + ((size_t)(b * T_ + qrow)) * C_ + h * DH_;
#pragma unroll
    for (int n = 0; n < 4; ++n)
      orow[n * 16 + l15] = __float2bfloat16(o[n][r] * inv);
  }
}

// ---------------- launch ----------------
extern "C" void kernel_launch(void* const* d_in, const int* in_sizes, int n_in,
                              void* d_out, int out_size, void* d_ws, size_t ws_size,
                              hipStream_t stream) {
  const float* x      = (const float*)d_in[0];
  const float* qkv_w  = (const float*)d_in[1];
  const float* qkv_b  = (const float*)d_in[2];
  const float* proj_w = (const float*)d_in[3];
  const float* proj_b = (const float*)d_in[4];
  float* out = (float*)d_out;

  char* ws = (char*)d_ws;
  __hip_bfloat16* xb    = (__hip_bfloat16*)(ws);                 // 16 MB
  __hip_bfloat16* wqkv  = (__hip_bfloat16*)(ws + 16777216);      // 6 MB
  __hip_bfloat16* wproj = (__hip_bfloat16*)(ws + 23068672);      // 2 MB
  __hip_bfloat16* qb    = (__hip_bfloat16*)(ws + 25165824);      // 16 MB
  __hip_bfloat16* kb    = (__hip_bfloat16*)(ws + 41943040);      // 16 MB
  __hip_bfloat16* vb    = (__hip_bfloat16*)(ws + 58720256);      // 16 MB
  __hip_bfloat16* att   = (__hip_bfloat16*)(ws + 75497472);      // 16 MB
  // total 92,274,688 bytes of d_ws

  cvt_f32_bf16<<<2048, 256, 0, stream>>>(x, xb, M_ * K_ / 4);
  cvt_f32_bf16<<<1024, 256, 0, stream>>>(qkv_w, wqkv, NQKV_ * K_ / 4);
  cvt_f32_bf16<<<512, 256, 0, stream>>>(proj_w, wproj, C_ * K_ / 4);

  gemm_bt<<<dim3(NQKV_ / 128, M_ / 128), 256, 0, stream>>>(
      xb, wqkv, qkv_b, 0, qb, kb, vb, nullptr);

  attn_kernel<<<dim3(B_ * H_ * (T_ / 64)), 256, 0, stream>>>(qb, kb, vb, att);

  gemm_bt<<<dim3(C_ / 128, M_ / 128), 256, 0, stream>>>(
      att, wproj, proj_b, 1, nullptr, nullptr, nullptr, out);
}

// Round 2
// 268.765 us; speedup vs baseline: 2.0663x; 2.0663x over previous
//
#include <hip/hip_runtime.h>
#include <hip/hip_bf16.h>
#include <stdint.h>

#define B_ 4
#define T_ 2048
#define C_ 1024
#define H_ 16
#define DH_ 64
#define M_ (B_*T_)      // 8192
#define NQKV_ (3*C_)    // 3072
#define K_ C_           // 1024

typedef __attribute__((ext_vector_type(8))) short short8;
typedef __attribute__((ext_vector_type(4))) float f32x4;
typedef __attribute__((ext_vector_type(4))) unsigned short us4;

union BFC { __hip_bfloat16 h; unsigned short u; };
__device__ inline unsigned short f2b(float f){ BFC c; c.h = __float2bfloat16(f); return c.u; }

__device__ inline void gload_lds16(const void* g, void* l){
  __builtin_amdgcn_global_load_lds(
    (const __attribute__((address_space(1))) void*)(uintptr_t)g,
    (__attribute__((address_space(3))) void*)(uintptr_t)l,
    16, 0, 0);
}

// ---------------- fp32 -> bf16 convert ----------------
__global__ void cvt_f32_bf16(const float* __restrict__ src,
                             __hip_bfloat16* __restrict__ dst, int n4)
{
  int i = blockIdx.x * blockDim.x + threadIdx.x;
  int stride = gridDim.x * blockDim.x;
  for (; i < n4; i += stride) {
    float4 v = reinterpret_cast<const float4*>(src)[i];
    us4 o;
    o.x = f2b(v.x); o.y = f2b(v.y); o.z = f2b(v.z); o.w = f2b(v.w);
    reinterpret_cast<us4*>(dst)[i] = o;
  }
}

// ---------------- GEMM: Y[M,N] = A[M,K] * B[N,K]^T + bias ----------------
// tile 128x128, BK=32, 4 waves (2x2), each wave 64x64 (4x4 of 16x16x32 MFMA)
// mode 0: scatter Q,K as [B,H,T,DH] and V TRANSPOSED as [B,H,DH,T]
__global__ __launch_bounds__(256) void gemm_bt(
    const __hip_bfloat16* __restrict__ A,
    const __hip_bfloat16* __restrict__ Bw,
    const float* __restrict__ bias,
    int mode,
    __hip_bfloat16* __restrict__ qdst,
    __hip_bfloat16* __restrict__ kdst,
    __hip_bfloat16* __restrict__ vdst,
    float* __restrict__ fdst)
{
  __shared__ char a_lds[8192];
  __shared__ char b_lds[8192];

  const int tid = threadIdx.x;
  const int lane = tid & 63;
  const int w = tid >> 6;
  const int l15 = lane & 15;
  const int lhi = lane >> 4;
  const int wm = w >> 1, wn = w & 1;
  const int row0 = blockIdx.y * 128;
  const int col0 = blockIdx.x * 128;

  int srow[2], scol[2];
#pragma unroll
  for (int j = 0; j < 2; ++j) {
    int L = w * 2048 + j * 1024 + lane * 16;
    int r = L >> 6;
    int cb = (L & 63) ^ (((r >> 1) & 3) << 4);
    srow[j] = r;
    scol[j] = cb >> 1;
  }

  const f32x4 zf = {0.f, 0.f, 0.f, 0.f};
  f32x4 acc[4][4];
#pragma unroll
  for (int m = 0; m < 4; ++m)
#pragma unroll
    for (int n = 0; n < 4; ++n) acc[m][n] = zf;

  const short* Ag = (const short*)A;
  const short* Bg = (const short*)Bw;

  for (int kt = 0; kt < K_; kt += 32) {
    gload_lds16(Ag + (size_t)(row0 + srow[0]) * K_ + kt + scol[0], a_lds + w * 2048);
    gload_lds16(Ag + (size_t)(row0 + srow[1]) * K_ + kt + scol[1], a_lds + w * 2048 + 1024);
    gload_lds16(Bg + (size_t)(col0 + srow[0]) * K_ + kt + scol[0], b_lds + w * 2048);
    gload_lds16(Bg + (size_t)(col0 + srow[1]) * K_ + kt + scol[1], b_lds + w * 2048 + 1024);
    __syncthreads();

    short8 af[4], bfr[4];
#pragma unroll
    for (int m = 0; m < 4; ++m) {
      int r = wm * 64 + m * 16 + l15;
      af[m] = *(const short8*)(a_lds + r * 64 + ((lhi * 16) ^ (((r >> 1) & 3) << 4)));
    }
#pragma unroll
    for (int n = 0; n < 4; ++n) {
      int r = wn * 64 + n * 16 + l15;
      bfr[n] = *(const short8*)(b_lds + r * 64 + ((lhi * 16) ^ (((r >> 1) & 3) << 4)));
    }
#pragma unroll
    for (int m = 0; m < 4; ++m)
#pragma unroll
      for (int n = 0; n < 4; ++n)
        acc[m][n] = __builtin_amdgcn_mfma_f32_16x16x32_bf16(af[m], bfr[n], acc[m][n], 0, 0, 0);
    __syncthreads();
  }

  if (mode == 0) {
#pragma unroll
    for (int m = 0; m < 4; ++m) {
#pragma unroll
      for (int r = 0; r < 4; ++r) {
        int grow = row0 + wm * 64 + m * 16 + lhi * 4 + r;
        int b = grow >> 11, tt = grow & 2047;
#pragma unroll
        for (int n = 0; n < 4; ++n) {
          int gcol = col0 + wn * 64 + n * 16 + l15;
          float v = acc[m][n][r] + bias[gcol];
          int sel = gcol >> 10;
          int c1 = gcol & 1023;
          int hh = c1 >> 6, dh = c1 & 63;
          __hip_bfloat16 bv = __float2bfloat16(v);
          if (sel == 0)
            qdst[(((size_t)(b * H_ + hh)) * T_ + tt) * DH_ + dh] = bv;
          else if (sel == 1)
            kdst[(((size_t)(b * H_ + hh)) * T_ + tt) * DH_ + dh] = bv;
          else  // V stored transposed: [B,H,DH,T]
            vdst[(((size_t)(b * H_ + hh)) * DH_ + dh) * T_ + tt] = bv;
        }
      }
    }
  } else {
#pragma unroll
    for (int m = 0; m < 4; ++m) {
#pragma unroll
      for (int r = 0; r < 4; ++r) {
        int grow = row0 + wm * 64 + m * 16 + lhi * 4 + r;
#pragma unroll
        for (int n = 0; n < 4; ++n) {
          int gcol = col0 + wn * 64 + n * 16 + l15;
          fdst[(size_t)grow * C_ + gcol] = acc[m][n][r] + bias[gcol];
        }
      }
    }
  }
}

// ---------------- causal flash attention, barrier-free ----------------
// grid = 8 chunks x 64 heads; block = 4 waves; each wave owns q-tile pair
// (j, 63-j) of 32 rows each -> uniform 33 KV-tiles of 64 per wave.
// K read direct from global [B,H,T,DH]; V read direct from V^T [B,H,DH,T].
// Only LDS: per-wave 4KB P buffer (wave-coherent, no barriers anywhere).
__global__ __launch_bounds__(256, 2) void attn_kernel(
    const __hip_bfloat16* __restrict__ qg,
    const __hip_bfloat16* __restrict__ kg,
    const __hip_bfloat16* __restrict__ vtg,
    __hip_bfloat16* __restrict__ og)
{
  __shared__ char p_lds[4 * 4096];  // per-wave [32][64] bf16, swizzle ((row&7)<<4)

  const int tid = threadIdx.x;
  const int lane = tid & 63;
  const int w = tid >> 6;
  const int l15 = lane & 15;
  const int lhi = lane >> 4;
  const int blk = blockIdx.x;
  const int bh = blk & 63;        // same-head blocks share XCD (blk%8 == bh%8)
  const int c = blk >> 6;         // 0..7
  const int pw = c * 4 + w;       // 0..31

  const short* qp = (const short*)(qg + (size_t)bh * T_ * DH_);
  const short* kp = (const short*)(kg + (size_t)bh * T_ * DH_);
  const short* vtp = (const short*)(vtg + (size_t)bh * DH_ * T_);
  const int b = bh >> 4, h = bh & 15;
  char* pwl = p_lds + w * 4096;

  for (int job = 0; job < 2; ++job) {
    const int j = job ? (63 - pw) : pw;
    const int qr0 = j * 32;

    short8 qf[2][2];
#pragma unroll
    for (int m = 0; m < 2; ++m)
#pragma unroll
      for (int kf = 0; kf < 2; ++kf)
        qf[m][kf] = *(const short8*)(qp + (size_t)(qr0 + m * 16 + l15) * DH_ +
                                     kf * 32 + lhi * 8);

    const f32x4 zf = {0.f, 0.f, 0.f, 0.f};
    f32x4 o[2][4];
    float mrow[2][4], lrow[2][4];
#pragma unroll
    for (int m = 0; m < 2; ++m)
#pragma unroll
      for (int n = 0; n < 4; ++n) o[m][n] = zf;
#pragma unroll
    for (int m = 0; m < 2; ++m)
#pragma unroll
      for (int r = 0; r < 4; ++r) { mrow[m][r] = -1e30f; lrow[m][r] = 0.f; }

    const int nt = (j >> 1) + 1;
    for (int t = 0; t < nt; ++t) {
      const int kv0 = t * 64;

      // issue all 16 fragment loads up front (L2-resident, deep ILP)
      short8 kfr[2][4], vfr[2][4];
#pragma unroll
      for (int kf = 0; kf < 2; ++kf)
#pragma unroll
        for (int n = 0; n < 4; ++n)
          kfr[kf][n] = *(const short8*)(kp + (size_t)(kv0 + n * 16 + l15) * DH_ +
                                        kf * 32 + lhi * 8);
#pragma unroll
      for (int kf = 0; kf < 2; ++kf)
#pragma unroll
        for (int n = 0; n < 4; ++n)
          vfr[kf][n] = *(const short8*)(vtp + (size_t)(n * 16 + l15) * T_ +
                                        kv0 + kf * 32 + lhi * 8);

      // S = Q K^T
      f32x4 s[2][4];
#pragma unroll
      for (int m = 0; m < 2; ++m)
#pragma unroll
        for (int n = 0; n < 4; ++n) s[m][n] = zf;
#pragma unroll
      for (int kf = 0; kf < 2; ++kf)
#pragma unroll
        for (int n = 0; n < 4; ++n)
#pragma unroll
          for (int m = 0; m < 2; ++m)
            s[m][n] = __builtin_amdgcn_mfma_f32_16x16x32_bf16(qf[m][kf], kfr[kf][n],
                                                              s[m][n], 0, 0, 0);
      const float scale = 0.125f;
#pragma unroll
      for (int m = 0; m < 2; ++m)
#pragma unroll
        for (int n = 0; n < 4; ++n)
#pragma unroll
          for (int r = 0; r < 4; ++r) s[m][n][r] *= scale;

      if (t == nt - 1) {
#pragma unroll
        for (int m = 0; m < 2; ++m)
#pragma unroll
          for (int n = 0; n < 4; ++n)
#pragma unroll
            for (int r = 0; r < 4; ++r) {
              int kvA = kv0 + n * 16 + l15;
              int qA = qr0 + m * 16 + lhi * 4 + r;
              if (kvA > qA) s[m][n][r] = -1e30f;
            }
      }

      // online softmax per row (row = m*16 + lhi*4 + r, spread across l15)
#pragma unroll
      for (int m = 0; m < 2; ++m) {
        float pm[4], rs[4];
#pragma unroll
        for (int r = 0; r < 4; ++r)
          pm[r] = fmaxf(fmaxf(s[m][0][r], s[m][1][r]),
                        fmaxf(s[m][2][r], s[m][3][r]));
#pragma unroll
        for (int r = 0; r < 4; ++r)
#pragma unroll
          for (int d = 1; d < 16; d <<= 1)
            pm[r] = fmaxf(pm[r], __shfl_xor(pm[r], d, 64));

        float alpha[4];
#pragma unroll
        for (int r = 0; r < 4; ++r) {
          float mn = fmaxf(mrow[m][r], pm[r]);
          alpha[r] = __expf(mrow[m][r] - mn);
          mrow[m][r] = mn;
          rs[r] = 0.f;
        }
#pragma unroll
        for (int n = 0; n < 4; ++n)
#pragma unroll
          for (int r = 0; r < 4; ++r) {
            float pe = __expf(s[m][n][r] - mrow[m][r]);
            s[m][n][r] = pe;
            rs[r] += pe;
          }
#pragma unroll
        for (int r = 0; r < 4; ++r) {
#pragma unroll
          for (int d = 1; d < 16; d <<= 1) rs[r] += __shfl_xor(rs[r], d, 64);
          lrow[m][r] = lrow[m][r] * alpha[r] + rs[r];
        }
#pragma unroll
        for (int n = 0; n < 4; ++n)
#pragma unroll
          for (int r = 0; r < 4; ++r) o[m][n][r] *= alpha[r];
      }

      // P -> per-wave LDS (bf16, swizzled), read back as MFMA A fragments
#pragma unroll
      for (int m = 0; m < 2; ++m)
#pragma unroll
        for (int n = 0; n < 4; ++n)
#pragma unroll
          for (int r = 0; r < 4; ++r) {
            int row = m * 16 + lhi * 4 + r;
            *(unsigned short*)(pwl + row * 128 +
                               (((n * 16 + l15) * 2) ^ ((row & 7) << 4))) =
                f2b(s[m][n][r]);
          }
      short8 pa[2][2];
#pragma unroll
      for (int m = 0; m < 2; ++m)
#pragma unroll
        for (int kf = 0; kf < 2; ++kf) {
          int row = m * 16 + l15;
          pa[m][kf] = *(const short8*)(pwl + row * 128 +
                                       ((kf * 64 + lhi * 16) ^ ((row & 7) << 4)));
        }

      // O += P V
#pragma unroll
      for (int kf = 0; kf < 2; ++kf)
#pragma unroll
        for (int n = 0; n < 4; ++n)
#pragma unroll
          for (int m = 0; m < 2; ++m)
            o[m][n] = __builtin_amdgcn_mfma_f32_16x16x32_bf16(pa[m][kf], vfr[kf][n],
                                                              o[m][n], 0, 0, 0);
    }

    // epilogue: O/l -> att [B,T,C] bf16 (c = h*64+dh)
#pragma unroll
    for (int m = 0; m < 2; ++m)
#pragma unroll
      for (int r = 0; r < 4; ++r) {
        float inv = 1.f / lrow[m][r];
        int qrow = qr0 + m * 16 + lhi * 4 + r;
        __hip_bfloat16* orow = og + ((size_t)(b * T_ + qrow)) * C_ + h * DH_;
#pragma unroll
        for (int n = 0; n < 4; ++n)
          orow[n * 16 + l15] = __float2bfloat16(o[m][n][r] * inv);
      }
  }
}

// ---------------- launch ----------------
extern "C" void kernel_launch(void* const* d_in, const int* in_sizes, int n_in,
                              void* d_out, int out_size, void* d_ws, size_t ws_size,
                              hipStream_t stream) {
  const float* x      = (const float*)d_in[0];
  const float* qkv_w  = (const float*)d_in[1];
  const float* qkv_b  = (const float*)d_in[2];
  const float* proj_w = (const float*)d_in[3];
  const float* proj_b = (const float*)d_in[4];
  float* out = (float*)d_out;

  char* ws = (char*)d_ws;
  __hip_bfloat16* xb    = (__hip_bfloat16*)(ws);                 // 16 MB
  __hip_bfloat16* wqkv  = (__hip_bfloat16*)(ws + 16777216);      // 6 MB
  __hip_bfloat16* wproj = (__hip_bfloat16*)(ws + 23068672);      // 2 MB
  __hip_bfloat16* qb    = (__hip_bfloat16*)(ws + 25165824);      // 16 MB
  __hip_bfloat16* kb    = (__hip_bfloat16*)(ws + 41943040);      // 16 MB
  __hip_bfloat16* vtb   = (__hip_bfloat16*)(ws + 58720256);      // 16 MB (V^T)
  __hip_bfloat16* att   = (__hip_bfloat16*)(ws + 75497472);      // 16 MB

  cvt_f32_bf16<<<2048, 256, 0, stream>>>(x, xb, M_ * K_ / 4);
  cvt_f32_bf16<<<1024, 256, 0, stream>>>(qkv_w, wqkv, NQKV_ * K_ / 4);
  cvt_f32_bf16<<<512, 256, 0, stream>>>(proj_w, wproj, C_ * K_ / 4);

  gemm_bt<<<dim3(NQKV_ / 128, M_ / 128), 256, 0, stream>>>(
      xb, wqkv, qkv_b, 0, qb, kb, vtb, nullptr);

  attn_kernel<<<dim3(512), 256, 0, stream>>>(qb, kb, vtb, att);

  gemm_bt<<<dim3(C_ / 128, M_ / 128), 256, 0, stream>>>(
      att, wproj, proj_b, 1, nullptr, nullptr, nullptr, out);
}